// Round 5
// baseline (245.237 us; speedup 1.0000x reference)
//
#include <hip/hip_runtime.h>

typedef _Float16 half8 __attribute__((ext_vector_type(8)));
typedef _Float16 half4 __attribute__((ext_vector_type(4)));
typedef float f32x4 __attribute__((ext_vector_type(4)));
typedef float f32x16 __attribute__((ext_vector_type(16)));
typedef unsigned int uint;
typedef uint uint2v __attribute__((ext_vector_type(2)));
typedef uint uint4v __attribute__((ext_vector_type(4)));

#define MFMA16(a, b, c) __builtin_amdgcn_mfma_f32_16x16x32_f16((a), (b), (c), 0, 0, 0)
#define MFMA32(a, b, c) __builtin_amdgcn_mfma_f32_32x32x16_f16((a), (b), (c), 0, 0, 0)

// async global->LDS, 16B per lane, dest = wave-uniform base + lane*16
#define GLOAD16(g, l)                                            \
    __builtin_amdgcn_global_load_lds(                            \
        (const __attribute__((address_space(1))) void*)(g),      \
        (__attribute__((address_space(3))) void*)(l), 16, 0, 0)

// B=2, N=2048, C=1024, H=16, D=64; M = B*N = 4096 tokens.
// qkv buffer layout: [s][b][h][n][d], s-stride = 2*16*2048*64 = 4194304 elems.
// q rows are stored LN'd AND pre-scaled by 0.125*log2(e) (folded into gemm1 epilogue, f32).

// ---------------------------------------------------------------- fused fp32 -> fp16 (x, w_qkv, w_proj)
__global__ __launch_bounds__(256) void cvt_all(const float* __restrict__ x,
                                               const float* __restrict__ wq,
                                               const float* __restrict__ wp,
                                               _Float16* __restrict__ xh,
                                               _Float16* __restrict__ wqh,
                                               _Float16* __restrict__ wph) {
    int i = blockIdx.x * 256 + threadIdx.x;  // 1,048,576 half8 units
    const float* src;
    _Float16* dst;
    int off;
    if (i < 524288) { src = x; dst = xh; off = i; }
    else if (i < 917504) { src = wq; dst = wqh; off = i - 524288; }
    else { src = wp; dst = wph; off = i - 917504; }
    const float4* p = reinterpret_cast<const float4*>(src) + 2 * (size_t)off;
    float4 a = p[0], b = p[1];
    half8 o;
    o[0] = (_Float16)a.x; o[1] = (_Float16)a.y; o[2] = (_Float16)a.z; o[3] = (_Float16)a.w;
    o[4] = (_Float16)b.x; o[5] = (_Float16)b.y; o[6] = (_Float16)b.z; o[7] = (_Float16)b.w;
    reinterpret_cast<half8*>(dst)[off] = o;
}

// ---------------------------------------------------------------- GEMM (NT), 2-phase pipelined:
// (MT*32) x (NT*32) tile, BK=64, double-buffered global_load_lds staging,
// XOR-swizzled linear LDS, XCD-swizzled grid (gridDim.x == 64 m-tiles, pow2).
// Loop: stage(t+1, buf^1) -> compute(t, buf) -> barrier  (loads overlap MFMA).
// EPI 0 (requires NT=4): fused per-head LayerNorm on q,k + scatter to qkv fp16.
// EPI 1: fp32 out [m][n].
template <int MT, int NT, int EPI>
__global__ __launch_bounds__(256) void gemm_nt(const _Float16* __restrict__ A,
                                               const _Float16* __restrict__ W,
                                               const float* __restrict__ bias,
                                               void* __restrict__ Cout, int K,
                                               const float* __restrict__ qg,
                                               const float* __restrict__ qb,
                                               const float* __restrict__ kg,
                                               const float* __restrict__ kb) {
    constexpr int TM = MT * 32;
    constexpr int TN = NT * 32;
    __shared__ __align__(16) _Float16 Al[2][TM * 64];
    __shared__ __align__(16) _Float16 Wl[2][TN * 64];
    const int tid = threadIdx.x, l = tid & 63, w = tid >> 6;
    const int lin = blockIdx.x + (blockIdx.y << 6);  // gridDim.x == 64
    const int nwg = gridDim.x * gridDim.y;
    const int wg = (lin & 7) * (nwg >> 3) + (lin >> 3);
    const int bm = (wg & 63) * TM, bn = (wg >> 6) * TN;
    const int wr = (w >> 1) * (MT * 16), wc = (w & 1) * (NT * 16);
    const int srow = l >> 3;               // 0..7
    const int schunk = (l & 7) ^ srow;     // pre-swizzled source 16B-chunk (rule #21)

    const _Float16* Ag = A + (size_t)(bm + (TM / 4) * w + srow) * K + 8 * schunk;
    const _Float16* Wg = W + (size_t)(bn + (TN / 4) * w + srow) * K + 8 * schunk;
    const int rswz = (l & 7) << 3;         // read-side XOR (halfs)
    const int nk = K >> 6;

    auto stage = [&](int t, int buf) {
        const int kt = t << 6;
#pragma unroll
        for (int i = 0; i < MT; i++)
            GLOAD16(Ag + (size_t)(8 * i) * K + kt, &Al[buf][((TM / 4) * w + 8 * i) * 64]);
#pragma unroll
        for (int i = 0; i < NT; i++)
            GLOAD16(Wg + (size_t)(8 * i) * K + kt, &Wl[buf][((TN / 4) * w + 8 * i) * 64]);
    };

    f32x4 acc[MT][NT] = {};
    stage(0, 0);
    __syncthreads();
    for (int t = 0; t < nk; ++t) {
        const int cur = t & 1;
        if (t + 1 < nk) stage(t + 1, cur ^ 1);  // async loads fly under compute
#pragma unroll
        for (int ks = 0; ks < 2; ks++) {
            const int koff = (ks * 32 + (l >> 4) * 8) ^ rswz;
            half8 af[MT], wf[NT];
#pragma unroll
            for (int i = 0; i < MT; i++)
                af[i] = *(const half8*)&Al[cur][(wr + i * 16 + (l & 15)) * 64 + koff];
#pragma unroll
            for (int i = 0; i < NT; i++)
                wf[i] = *(const half8*)&Wl[cur][(wc + i * 16 + (l & 15)) * 64 + koff];
            __builtin_amdgcn_s_setprio(1);
#pragma unroll
            for (int mt = 0; mt < MT; mt++)
#pragma unroll
                for (int nt = 0; nt < NT; nt++)
                    acc[mt][nt] = MFMA16(af[mt], wf[nt], acc[mt][nt]);
            __builtin_amdgcn_s_setprio(0);
        }
        __syncthreads();
    }

    if (EPI == 0) {
        const int ncol = bn + wc;          // 64-aligned -> exactly one (s, head) d-window
        const int s = ncol >> 10;
        const int hh = (ncol >> 6) & 15;
        const float* gam = (s == 0) ? qg : kg;
        const float* bet = (s == 0) ? qb : kb;
        float ga[4], be[4];
        if (s < 2) {
#pragma unroll
            for (int nt = 0; nt < 4; nt++) {
                int d = nt * 16 + (l & 15);
                ga[nt] = gam[d];
                be[nt] = bet[d];
            }
        }
        const float cs = (s == 0) ? 0.18033688f : 1.f;  // 0.125*log2(e) folded into q
#pragma unroll
        for (int mt = 0; mt < MT; mt++)
#pragma unroll
            for (int r = 0; r < 4; r++) {
                float v[4];
                float sm = 0.f, s2 = 0.f;
#pragma unroll
                for (int nt = 0; nt < 4; nt++) {
                    v[nt] = acc[mt][nt][r] + bias[ncol + nt * 16 + (l & 15)];
                    sm += v[nt];
                    s2 += v[nt] * v[nt];
                }
                int m = bm + wr + mt * 16 + (l >> 4) * 4 + r;
                int b = m >> 11, nn = m & 2047;
                _Float16* dst = (_Float16*)Cout +
                    (size_t)((((s * 2 + b) * 16 + hh) * 2048 + nn) << 6);
                if (s < 2) {
#pragma unroll
                    for (int off = 1; off < 16; off <<= 1) {
                        sm += __shfl_xor(sm, off);
                        s2 += __shfl_xor(s2, off);
                    }
                    float mean = sm * (1.f / 64.f);
                    float var = s2 * (1.f / 64.f) - mean * mean;
                    float rs = rsqrtf(var + 1e-5f) * cs;
#pragma unroll
                    for (int nt = 0; nt < 4; nt++) {
                        int d = nt * 16 + (l & 15);
                        dst[d] = (_Float16)((v[nt] - mean) * rs * ga[nt] + be[nt] * cs);
                    }
                } else {
#pragma unroll
                    for (int nt = 0; nt < 4; nt++)
                        dst[nt * 16 + (l & 15)] = (_Float16)v[nt];
                }
            }
    } else {
#pragma unroll
        for (int mt = 0; mt < MT; mt++)
#pragma unroll
            for (int nt = 0; nt < NT; nt++)
#pragma unroll
                for (int r = 0; r < 4; r++) {
                    int m = bm + wr + mt * 16 + (l >> 4) * 4 + r;
                    int n = bn + wc + nt * 16 + (l & 15);
                    ((float*)Cout)[(size_t)m * 1024 + n] = acc[mt][nt][r] + bias[n];
                }
    }
}

// ---------------------------------------------------------------- flash attention, swapped-QK^T 32x32
// SPLIT=4: grid 2048 (4 KV-quarters), 8 iters, writes fp16 numerator partials + f32 l partials
//          (no-max softmax => partials merge by plain summation).
// No online max: q pre-scaled by 0.125*log2e => s' <= 11.6, p = 2^s' <= 2980 fits fp16.
// __launch_bounds__(256, 4): cap combined VGPR+AGPR at 128 -> 4 waves/SIMD residency.
template <int SPLIT>
__global__ __launch_bounds__(256, 4) void attn_kernel(const _Float16* __restrict__ qkv,
                                                      _Float16* __restrict__ out,
                                                      float* __restrict__ lpart) {
    const int tid = threadIdx.x;
    const int l = tid & 63, w = tid >> 6;
    const int l31 = l & 31, hi = l >> 5;
    const int bid = blockIdx.x;
    const int nwg = 512 * SPLIT;
    const int wg = (bid & 7) * (nwg >> 3) + (bid >> 3);  // bijective XCD chunking
    int head, qt, quarter;
    if (SPLIT == 4) { head = wg >> 6; qt = (wg >> 2) & 15; quarter = wg & 3; }
    else            { head = wg >> 4; qt = wg & 15;        quarter = 0; }
    const int b = head >> 4, h = head & 15;
    const size_t hstride = (size_t)2048 * 64;
    const _Float16* Q = qkv + (size_t)((0 + b) * 16 + h) * hstride;
    const _Float16* Kp = qkv + (size_t)((2 + b) * 16 + h) * hstride + (size_t)quarter * 512 * 64;
    const _Float16* Vp = qkv + (size_t)((4 + b) * 16 + h) * hstride + (size_t)quarter * 512 * 64;
    const int NIT = (SPLIT == 4) ? 8 : 32;

    __shared__ __align__(16) _Float16 Kl[2][64 * 64];  // [k][d], chunk ^= (k&7)
    __shared__ __align__(16) _Float16 Vt[2][64 * 64];  // [d][k], slot ^= (d&7)^((d>>3)&7)

    // ---- Q fragments (B-operand): Q[q=l31][d = 16*dk + 8*hi + i] (already LN'd + scaled)
    const int r0q = qt * 128 + w * 32;
    half8 qf[4];
    {
        const _Float16* Qrow = Q + (size_t)(r0q + l31) * 64 + 8 * hi;
#pragma unroll
        for (int dk = 0; dk < 4; dk++) qf[dk] = *(const half8*)&Qrow[16 * dk];
    }

    const int srow = l >> 3, sch = l & 7;
    auto stageK = [&](int it, _Float16* dst) {
#pragma unroll
        for (int t = 0; t < 2; t++) {
            int r0 = 16 * w + 8 * t;
            const _Float16* g = Kp + (size_t)(it * 64 + r0 + srow) * 64 + 8 * (sch ^ srow);
            GLOAD16(g, &dst[r0 * 64]);
        }
    };
    auto loadV = [&](int it, half8& v0, half8& v1) {
        const _Float16* g = Vp + (size_t)(it * 64 + 16 * w + srow) * 64 + 8 * sch;
        v0 = *(const half8*)g;
        v1 = *(const half8*)(g + 8 * 64);
    };
    auto scatterV = [&](half8 v0, half8 v1, _Float16* dst) {
        const int j0 = 16 * w + srow;
        const int d0 = 8 * sch;
#pragma unroll
        for (int i = 0; i < 8; i++) {
            const int sw = (i ^ sch) << 3;
            dst[(d0 + i) * 64 + (j0 ^ sw)] = v0[i];
            dst[(d0 + i) * 64 + ((j0 + 8) ^ sw)] = v1[i];
        }
    };

    float lrun = 0.f;
    f32x16 o0 = {}, o1 = {};

    half8 va, vb;
    stageK(0, Kl[0]);
    loadV(0, va, vb);
    scatterV(va, vb, Vt[0]);
    __syncthreads();

    const int kswz = (l31 & 7) << 3;
    const int vswz0 = ((l31 & 7) ^ (l31 >> 3)) << 3;
    const int vswz1 = vswz0 ^ (4 << 3);

    for (int it = 0; it < NIT; ++it) {
        const int cur = it & 1;
        const _Float16* Kc = Kl[cur];
        const _Float16* Vc = Vt[cur];
        if (it + 1 < NIT) {
            stageK(it + 1, Kl[cur ^ 1]);  // async, in flight across compute
            loadV(it + 1, va, vb);        // T14 issue-early
        }
        // ---- S'^T = K Q'^T (log2 domain)
        f32x16 st0 = {}, st1 = {};
#pragma unroll
        for (int dk = 0; dk < 4; dk++) {
            const int colr = 16 * dk + 8 * hi;
            half8 kf0 = *(const half8*)&Kc[l31 * 64 + (colr ^ kswz)];
            half8 kf1 = *(const half8*)&Kc[(32 + l31) * 64 + (colr ^ kswz)];
            __builtin_amdgcn_s_setprio(1);
            st0 = MFMA32(kf0, qf[dk], st0);
            st1 = MFMA32(kf1, qf[dk], st1);
            __builtin_amdgcn_s_setprio(0);
        }
        // ---- softmax numerator, no max tracking: p = 2^s', lane-local sum
        float lh = 0.f;
#pragma unroll
        for (int r = 0; r < 16; r++) { st0[r] = exp2f(st0[r]); lh += st0[r]; }
#pragma unroll
        for (int r = 0; r < 16; r++) { st1[r] = exp2f(st1[r]); lh += st1[r]; }
        lrun += lh;

        // ---- P fragments in-register (cvt_pkrtz + permlane32_swap, T12) + PV
#define PV_CHUNK(stv, c)                                                                   \
        {                                                                                  \
            uint pk0 = __builtin_bit_cast(uint, __builtin_amdgcn_cvt_pkrtz(stv[(c & 1) * 8 + 0], stv[(c & 1) * 8 + 1])); \
            uint pk1 = __builtin_bit_cast(uint, __builtin_amdgcn_cvt_pkrtz(stv[(c & 1) * 8 + 2], stv[(c & 1) * 8 + 3])); \
            uint pk2 = __builtin_bit_cast(uint, __builtin_amdgcn_cvt_pkrtz(stv[(c & 1) * 8 + 4], stv[(c & 1) * 8 + 5])); \
            uint pk3 = __builtin_bit_cast(uint, __builtin_amdgcn_cvt_pkrtz(stv[(c & 1) * 8 + 6], stv[(c & 1) * 8 + 7])); \
            uint2v s02 = __builtin_amdgcn_permlane32_swap(pk0, pk2, false, false);         \
            uint2v s13 = __builtin_amdgcn_permlane32_swap(pk1, pk3, false, false);         \
            uint4v fu = {s02.x, s13.x, s02.y, s13.y};                                      \
            half8 pfrag = __builtin_bit_cast(half8, fu);                                   \
            const int colc = 16 * (c) + 8 * hi;                                            \
            half8 vf0 = *(const half8*)&Vc[l31 * 64 + (colc ^ vswz0)];                     \
            half8 vf1 = *(const half8*)&Vc[(32 + l31) * 64 + (colc ^ vswz1)];              \
            __builtin_amdgcn_s_setprio(1);                                                 \
            o0 = MFMA32(vf0, pfrag, o0);                                                   \
            o1 = MFMA32(vf1, pfrag, o1);                                                   \
            __builtin_amdgcn_s_setprio(0);                                                 \
        }
        PV_CHUNK(st0, 0)
        PV_CHUNK(st0, 1)
        PV_CHUNK(st1, 2)
        PV_CHUNK(st1, 3)
#undef PV_CHUNK

        if (it + 1 < NIT) scatterV(va, vb, Vt[cur ^ 1]);
        __syncthreads();
    }

    // ---- epilogue
    lrun += __shfl_xor(lrun, 32);
    const int tok = r0q + l31;
    if (SPLIT == 4) {
        // write raw numerators (exact-sum merge later) + partial l
        _Float16* orow = out + (size_t)quarter * 4194304 + (size_t)(b * 2048 + tok) * 1024 + h * 64;
#pragma unroll
        for (int g = 0; g < 4; g++) {
            half4 h4a, h4b;
#pragma unroll
            for (int j = 0; j < 4; j++) {
                h4a[j] = (_Float16)o0[4 * g + j];
                h4b[j] = (_Float16)o1[4 * g + j];
            }
            *(half4*)&orow[8 * g + 4 * hi] = h4a;
            *(half4*)&orow[32 + 8 * g + 4 * hi] = h4b;
        }
        if (!hi) lpart[quarter * 65536 + (b * 16 + h) * 2048 + tok] = lrun;
    } else {
        const float inv = __builtin_amdgcn_rcpf(lrun);
        _Float16* orow = out + (size_t)(b * 2048 + tok) * 1024 + h * 64;
#pragma unroll
        for (int g = 0; g < 4; g++) {
            half4 h4a, h4b;
#pragma unroll
            for (int j = 0; j < 4; j++) {
                h4a[j] = (_Float16)(o0[4 * g + j] * inv);
                h4b[j] = (_Float16)(o1[4 * g + j] * inv);
            }
            *(half4*)&orow[8 * g + 4 * hi] = h4a;
            *(half4*)&orow[32 + 8 * g + 4 * hi] = h4b;
        }
    }
}

// ---------------------------------------------------------------- split-KV merge: attnh = (sum numerators)/(sum l)
__global__ __launch_bounds__(256) void merge_attn(const _Float16* __restrict__ onum,
                                                  const float* __restrict__ lpart,
                                                  _Float16* __restrict__ attnh) {
    const int i = blockIdx.x * 256 + threadIdx.x;  // [0, 524288) half8 units
    const int tokb = i >> 7;                       // b*2048 + tok
    const int c0 = (i & 127) * 8;
    const int h = c0 >> 6;
    const int bb = tokb >> 11, tok = tokb & 2047;
    const int li = (bb * 16 + h) * 2048 + tok;
    float lt = lpart[li] + lpart[65536 + li] + lpart[131072 + li] + lpart[196608 + li];
    float inv = __builtin_amdgcn_rcpf(lt);
    float acc[8] = {};
#pragma unroll
    for (int q = 0; q < 4; q++) {
        half8 v = *(const half8*)&onum[(size_t)q * 4194304 + (size_t)tokb * 1024 + c0];
#pragma unroll
        for (int j = 0; j < 8; j++) acc[j] += (float)v[j];
    }
    half8 o;
#pragma unroll
    for (int j = 0; j < 8; j++) o[j] = (_Float16)(acc[j] * inv);
    *(half8*)&attnh[(size_t)tokb * 1024 + c0] = o;
}

// ---------------------------------------------------------------- launch
extern "C" void kernel_launch(void* const* d_in, const int* in_sizes, int n_in,
                              void* d_out, int out_size, void* d_ws, size_t ws_size,
                              hipStream_t stream) {
    const float* x = (const float*)d_in[0];
    const float* w_qkv = (const float*)d_in[1];
    const float* b_qkv = (const float*)d_in[2];
    const float* q_gamma = (const float*)d_in[3];
    const float* q_beta = (const float*)d_in[4];
    const float* k_gamma = (const float*)d_in[5];
    const float* k_beta = (const float*)d_in[6];
    const float* w_proj = (const float*)d_in[7];
    const float* b_proj = (const float*)d_in[8];

    char* ws = (char*)d_ws;
    _Float16* xh = (_Float16*)(ws + 0);             // 4096*1024
    _Float16* wqkvh = (_Float16*)(ws + 8388608);    // 3072*1024
    _Float16* wprojh = (_Float16*)(ws + 14680064);  // 1024*1024
    _Float16* qkvh = (_Float16*)(ws + 16777216);    // 3*2*16*2048*64
    _Float16* attnh = (_Float16*)(ws + 41943040);   // 4096*1024
    _Float16* onum = (_Float16*)(ws + 50331648);    // 4 * 4096*1024 fp16 = 32 MB
    float* lp = (float*)(ws + 83886080);            // 4 * 65536 f32 = 1 MB
    const bool split = ws_size >= 84934656;

    cvt_all<<<4096, 256, 0, stream>>>(x, w_qkv, w_proj, xh, wqkvh, wprojh);

    gemm_nt<2, 4, 0><<<dim3(64, 24), 256, 0, stream>>>(xh, wqkvh, b_qkv, (void*)qkvh, 1024,
                                                       q_gamma, q_beta, k_gamma, k_beta);

    if (split) {
        attn_kernel<4><<<2048, 256, 0, stream>>>(qkvh, onum, lp);
        merge_attn<<<2048, 256, 0, stream>>>(onum, lp, attnh);
    } else {
        attn_kernel<1><<<512, 256, 0, stream>>>(qkvh, attnh, nullptr);
    }

    gemm_nt<2, 2, 1><<<dim3(64, 16), 256, 0, stream>>>(attnh, wprojh, b_proj, d_out, 1024,
                                                       nullptr, nullptr, nullptr, nullptr);
}

// Round 6
// 224.839 us; speedup vs baseline: 1.0907x; 1.0907x over previous
//
#include <hip/hip_runtime.h>

typedef _Float16 half8 __attribute__((ext_vector_type(8)));
typedef _Float16 half4 __attribute__((ext_vector_type(4)));
typedef float f32x4 __attribute__((ext_vector_type(4)));
typedef float f32x16 __attribute__((ext_vector_type(16)));
typedef unsigned int uint;
typedef uint uint2v __attribute__((ext_vector_type(2)));
typedef uint uint4v __attribute__((ext_vector_type(4)));

#define MFMA16(a, b, c) __builtin_amdgcn_mfma_f32_16x16x32_f16((a), (b), (c), 0, 0, 0)
#define MFMA32(a, b, c) __builtin_amdgcn_mfma_f32_32x32x16_f16((a), (b), (c), 0, 0, 0)

// async global->LDS, 16B per lane, dest = wave-uniform base + lane*16
#define GLOAD16(g, l)                                            \
    __builtin_amdgcn_global_load_lds(                            \
        (const __attribute__((address_space(1))) void*)(g),      \
        (__attribute__((address_space(3))) void*)(l), 16, 0, 0)

// B=2, N=2048, C=1024, H=16, D=64; M = B*N = 4096 tokens.
// qkv buffer layout: [s][b][h][n][d], s-stride = 2*16*2048*64 = 4194304 elems.
// q rows are stored LN'd AND pre-scaled by 0.125*log2(e) (folded into gemm1 epilogue, f32).

// ---------------------------------------------------------------- fused fp32 -> fp16 (x, w_qkv, w_proj)
__global__ __launch_bounds__(256) void cvt_all(const float* __restrict__ x,
                                               const float* __restrict__ wq,
                                               const float* __restrict__ wp,
                                               _Float16* __restrict__ xh,
                                               _Float16* __restrict__ wqh,
                                               _Float16* __restrict__ wph) {
    int i = blockIdx.x * 256 + threadIdx.x;  // 1,048,576 half8 units
    const float* src;
    _Float16* dst;
    int off;
    if (i < 524288) { src = x; dst = xh; off = i; }
    else if (i < 917504) { src = wq; dst = wqh; off = i - 524288; }
    else { src = wp; dst = wph; off = i - 917504; }
    const float4* p = reinterpret_cast<const float4*>(src) + 2 * (size_t)off;
    float4 a = p[0], b = p[1];
    half8 o;
    o[0] = (_Float16)a.x; o[1] = (_Float16)a.y; o[2] = (_Float16)a.z; o[3] = (_Float16)a.w;
    o[4] = (_Float16)b.x; o[5] = (_Float16)b.y; o[6] = (_Float16)b.z; o[7] = (_Float16)b.w;
    reinterpret_cast<half8*>(dst)[off] = o;
}

// ---------------------------------------------------------------- GEMM (NT), 2-phase pipelined:
// (MT*32) x (NT*32) tile, BK=64, double-buffered global_load_lds staging,
// XOR-swizzled linear LDS, XCD-swizzled grid (gridDim.x == 64 m-tiles, pow2).
// Loop: stage(t+1, buf^1) -> compute(t, buf) -> barrier  (loads overlap MFMA).
// EPI 0 (requires NT=4): fused per-head LayerNorm on q,k + scatter to qkv fp16.
// EPI 1: fp32 out [m][n].
template <int MT, int NT, int EPI>
__global__ __launch_bounds__(256) void gemm_nt(const _Float16* __restrict__ A,
                                               const _Float16* __restrict__ W,
                                               const float* __restrict__ bias,
                                               void* __restrict__ Cout, int K,
                                               const float* __restrict__ qg,
                                               const float* __restrict__ qb,
                                               const float* __restrict__ kg,
                                               const float* __restrict__ kb) {
    constexpr int TM = MT * 32;
    constexpr int TN = NT * 32;
    __shared__ __align__(16) _Float16 Al[2][TM * 64];
    __shared__ __align__(16) _Float16 Wl[2][TN * 64];
    const int tid = threadIdx.x, l = tid & 63, w = tid >> 6;
    const int lin = blockIdx.x + (blockIdx.y << 6);  // gridDim.x == 64
    const int nwg = gridDim.x * gridDim.y;
    const int wg = (lin & 7) * (nwg >> 3) + (lin >> 3);
    const int bm = (wg & 63) * TM, bn = (wg >> 6) * TN;
    const int wr = (w >> 1) * (MT * 16), wc = (w & 1) * (NT * 16);
    const int srow = l >> 3;               // 0..7
    const int schunk = (l & 7) ^ srow;     // pre-swizzled source 16B-chunk (rule #21)

    const _Float16* Ag = A + (size_t)(bm + (TM / 4) * w + srow) * K + 8 * schunk;
    const _Float16* Wg = W + (size_t)(bn + (TN / 4) * w + srow) * K + 8 * schunk;
    const int rswz = (l & 7) << 3;         // read-side XOR (halfs)
    const int nk = K >> 6;

    auto stage = [&](int t, int buf) {
        const int kt = t << 6;
#pragma unroll
        for (int i = 0; i < MT; i++)
            GLOAD16(Ag + (size_t)(8 * i) * K + kt, &Al[buf][((TM / 4) * w + 8 * i) * 64]);
#pragma unroll
        for (int i = 0; i < NT; i++)
            GLOAD16(Wg + (size_t)(8 * i) * K + kt, &Wl[buf][((TN / 4) * w + 8 * i) * 64]);
    };

    f32x4 acc[MT][NT] = {};
    stage(0, 0);
    __syncthreads();
    for (int t = 0; t < nk; ++t) {
        const int cur = t & 1;
        if (t + 1 < nk) stage(t + 1, cur ^ 1);  // async loads fly under compute
#pragma unroll
        for (int ks = 0; ks < 2; ks++) {
            const int koff = (ks * 32 + (l >> 4) * 8) ^ rswz;
            half8 af[MT], wf[NT];
#pragma unroll
            for (int i = 0; i < MT; i++)
                af[i] = *(const half8*)&Al[cur][(wr + i * 16 + (l & 15)) * 64 + koff];
#pragma unroll
            for (int i = 0; i < NT; i++)
                wf[i] = *(const half8*)&Wl[cur][(wc + i * 16 + (l & 15)) * 64 + koff];
            __builtin_amdgcn_s_setprio(1);
#pragma unroll
            for (int mt = 0; mt < MT; mt++)
#pragma unroll
                for (int nt = 0; nt < NT; nt++)
                    acc[mt][nt] = MFMA16(af[mt], wf[nt], acc[mt][nt]);
            __builtin_amdgcn_s_setprio(0);
        }
        __syncthreads();
    }

    if (EPI == 0) {
        const int ncol = bn + wc;          // 64-aligned -> exactly one (s, head) d-window
        const int s = ncol >> 10;
        const int hh = (ncol >> 6) & 15;
        const float* gam = (s == 0) ? qg : kg;
        const float* bet = (s == 0) ? qb : kb;
        float ga[4], be[4];
        if (s < 2) {
#pragma unroll
            for (int nt = 0; nt < 4; nt++) {
                int d = nt * 16 + (l & 15);
                ga[nt] = gam[d];
                be[nt] = bet[d];
            }
        }
        const float cs = (s == 0) ? 0.18033688f : 1.f;  // 0.125*log2(e) folded into q
#pragma unroll
        for (int mt = 0; mt < MT; mt++)
#pragma unroll
            for (int r = 0; r < 4; r++) {
                float v[4];
                float sm = 0.f, s2 = 0.f;
#pragma unroll
                for (int nt = 0; nt < 4; nt++) {
                    v[nt] = acc[mt][nt][r] + bias[ncol + nt * 16 + (l & 15)];
                    sm += v[nt];
                    s2 += v[nt] * v[nt];
                }
                int m = bm + wr + mt * 16 + (l >> 4) * 4 + r;
                int b = m >> 11, nn = m & 2047;
                _Float16* dst = (_Float16*)Cout +
                    (size_t)((((s * 2 + b) * 16 + hh) * 2048 + nn) << 6);
                if (s < 2) {
#pragma unroll
                    for (int off = 1; off < 16; off <<= 1) {
                        sm += __shfl_xor(sm, off);
                        s2 += __shfl_xor(s2, off);
                    }
                    float mean = sm * (1.f / 64.f);
                    float var = s2 * (1.f / 64.f) - mean * mean;
                    float rs = rsqrtf(var + 1e-5f) * cs;
#pragma unroll
                    for (int nt = 0; nt < 4; nt++) {
                        int d = nt * 16 + (l & 15);
                        dst[d] = (_Float16)((v[nt] - mean) * rs * ga[nt] + be[nt] * cs);
                    }
                } else {
#pragma unroll
                    for (int nt = 0; nt < 4; nt++)
                        dst[nt * 16 + (l & 15)] = (_Float16)v[nt];
                }
            }
    } else {
#pragma unroll
        for (int mt = 0; mt < MT; mt++)
#pragma unroll
            for (int nt = 0; nt < NT; nt++)
#pragma unroll
                for (int r = 0; r < 4; r++) {
                    int m = bm + wr + mt * 16 + (l >> 4) * 4 + r;
                    int n = bn + wc + nt * 16 + (l & 15);
                    ((float*)Cout)[(size_t)m * 1024 + n] = acc[mt][nt][r] + bias[n];
                }
    }
}

// ---------------------------------------------------------------- flash attention, swapped-QK^T 32x32
// SPLIT=4: grid 2048 (4 KV-quarters), 8 iters, writes fp16 numerator partials + f32 l partials
//          (no-max softmax => partials merge by plain summation).
// No online max: q pre-scaled by 0.125*log2e => s' <= 11.6, p = 2^s' <= 2980 fits fp16.
// Two-half score pipeline: only 16 score f32 live at a time -> total regs fit 128
// (4 waves/SIMD via __launch_bounds__(256,4)) with no spills / no AGPR ping-pong.
template <int SPLIT>
__global__ __launch_bounds__(256, 4) void attn_kernel(const _Float16* __restrict__ qkv,
                                                      _Float16* __restrict__ out,
                                                      float* __restrict__ lpart) {
    const int tid = threadIdx.x;
    const int l = tid & 63, w = tid >> 6;
    const int l31 = l & 31, hi = l >> 5;
    const int bid = blockIdx.x;
    const int nwg = 512 * SPLIT;
    const int wg = (bid & 7) * (nwg >> 3) + (bid >> 3);  // bijective XCD chunking
    int head, qt, quarter;
    if (SPLIT == 4) { head = wg >> 6; qt = (wg >> 2) & 15; quarter = wg & 3; }
    else            { head = wg >> 4; qt = wg & 15;        quarter = 0; }
    const int b = head >> 4, h = head & 15;
    const size_t hstride = (size_t)2048 * 64;
    const _Float16* Q = qkv + (size_t)((0 + b) * 16 + h) * hstride;
    const _Float16* Kp = qkv + (size_t)((2 + b) * 16 + h) * hstride + (size_t)quarter * 512 * 64;
    const _Float16* Vp = qkv + (size_t)((4 + b) * 16 + h) * hstride + (size_t)quarter * 512 * 64;
    const int NIT = (SPLIT == 4) ? 8 : 32;

    __shared__ __align__(16) _Float16 Kl[2][64 * 64];  // [k][d], chunk ^= (k&7)
    __shared__ __align__(16) _Float16 Vt[2][64 * 64];  // [d][k], slot ^= (d&7)^((d>>3)&7)

    // ---- Q fragments (B-operand): Q[q=l31][d = 16*dk + 8*hi + i] (already LN'd + scaled)
    const int r0q = qt * 128 + w * 32;
    half8 qf[4];
    {
        const _Float16* Qrow = Q + (size_t)(r0q + l31) * 64 + 8 * hi;
#pragma unroll
        for (int dk = 0; dk < 4; dk++) qf[dk] = *(const half8*)&Qrow[16 * dk];
    }

    const int srow = l >> 3, sch = l & 7;
    auto stageK = [&](int it, _Float16* dst) {
#pragma unroll
        for (int t = 0; t < 2; t++) {
            int r0 = 16 * w + 8 * t;
            const _Float16* g = Kp + (size_t)(it * 64 + r0 + srow) * 64 + 8 * (sch ^ srow);
            GLOAD16(g, &dst[r0 * 64]);
        }
    };
    auto loadV = [&](int it, half8& v0, half8& v1) {
        const _Float16* g = Vp + (size_t)(it * 64 + 16 * w + srow) * 64 + 8 * sch;
        v0 = *(const half8*)g;
        v1 = *(const half8*)(g + 8 * 64);
    };
    auto scatterV = [&](half8 v0, half8 v1, _Float16* dst) {
        const int j0 = 16 * w + srow;
        const int d0 = 8 * sch;
#pragma unroll
        for (int i = 0; i < 8; i++) {
            const int sw = (i ^ sch) << 3;
            dst[(d0 + i) * 64 + (j0 ^ sw)] = v0[i];
            dst[(d0 + i) * 64 + ((j0 + 8) ^ sw)] = v1[i];
        }
    };

    float lrun = 0.f;
    f32x16 o0 = {}, o1 = {};

    half8 va, vb;
    stageK(0, Kl[0]);
    loadV(0, va, vb);
    scatterV(va, vb, Vt[0]);
    __syncthreads();

    const int kswz = (l31 & 7) << 3;
    const int vswz0 = ((l31 & 7) ^ (l31 >> 3)) << 3;
    const int vswz1 = vswz0 ^ (4 << 3);

    for (int it = 0; it < NIT; ++it) {
        const int cur = it & 1;
        const _Float16* Kc = Kl[cur];
        const _Float16* Vc = Vt[cur];
        if (it + 1 < NIT) {
            stageK(it + 1, Kl[cur ^ 1]);  // async, in flight across compute
            loadV(it + 1, va, vb);        // T14 issue-early
        }

        // ---- two half-passes over the KV tile: rows 32h..32h+31, chunks 2h, 2h+1
#pragma unroll
        for (int hf = 0; hf < 2; hf++) {
            // S'^T = K Q'^T (log2 domain), one 32-row half
            f32x16 st = {};
#pragma unroll
            for (int dk = 0; dk < 4; dk++) {
                const int colr = 16 * dk + 8 * hi;
                half8 kf = *(const half8*)&Kc[(hf * 32 + l31) * 64 + (colr ^ kswz)];
                __builtin_amdgcn_s_setprio(1);
                st = MFMA32(kf, qf[dk], st);
                __builtin_amdgcn_s_setprio(0);
            }
            // softmax numerator, no max tracking: p = 2^s'
#pragma unroll
            for (int r = 0; r < 16; r++) st[r] = exp2f(st[r]);
            // pairwise tree sum (breaks the serial FP-add chain)
            lrun += (((st[0] + st[1]) + (st[2] + st[3])) +
                     ((st[4] + st[5]) + (st[6] + st[7]))) +
                    (((st[8] + st[9]) + (st[10] + st[11])) +
                     ((st[12] + st[13]) + (st[14] + st[15])));

            // P fragments in-register (cvt_pkrtz + permlane32_swap, T12) + PV
#pragma unroll
            for (int cc = 0; cc < 2; cc++) {
                const int c = 2 * hf + cc;
                uint pk0 = __builtin_bit_cast(uint, __builtin_amdgcn_cvt_pkrtz(st[cc * 8 + 0], st[cc * 8 + 1]));
                uint pk1 = __builtin_bit_cast(uint, __builtin_amdgcn_cvt_pkrtz(st[cc * 8 + 2], st[cc * 8 + 3]));
                uint pk2 = __builtin_bit_cast(uint, __builtin_amdgcn_cvt_pkrtz(st[cc * 8 + 4], st[cc * 8 + 5]));
                uint pk3 = __builtin_bit_cast(uint, __builtin_amdgcn_cvt_pkrtz(st[cc * 8 + 6], st[cc * 8 + 7]));
                uint2v s02 = __builtin_amdgcn_permlane32_swap(pk0, pk2, false, false);
                uint2v s13 = __builtin_amdgcn_permlane32_swap(pk1, pk3, false, false);
                uint4v fu = {s02.x, s13.x, s02.y, s13.y};
                half8 pfrag = __builtin_bit_cast(half8, fu);
                const int colc = 16 * c + 8 * hi;
                half8 vf0 = *(const half8*)&Vc[l31 * 64 + (colc ^ vswz0)];
                half8 vf1 = *(const half8*)&Vc[(32 + l31) * 64 + (colc ^ vswz1)];
                __builtin_amdgcn_s_setprio(1);
                o0 = MFMA32(vf0, pfrag, o0);
                o1 = MFMA32(vf1, pfrag, o1);
                __builtin_amdgcn_s_setprio(0);
            }
        }

        if (it + 1 < NIT) scatterV(va, vb, Vt[cur ^ 1]);
        __syncthreads();
    }

    // ---- epilogue
    lrun += __shfl_xor(lrun, 32);
    const int tok = r0q + l31;
    if (SPLIT == 4) {
        // write raw numerators (exact-sum merge later) + partial l
        _Float16* orow = out + (size_t)quarter * 4194304 + (size_t)(b * 2048 + tok) * 1024 + h * 64;
#pragma unroll
        for (int g = 0; g < 4; g++) {
            half4 h4a, h4b;
#pragma unroll
            for (int j = 0; j < 4; j++) {
                h4a[j] = (_Float16)o0[4 * g + j];
                h4b[j] = (_Float16)o1[4 * g + j];
            }
            *(half4*)&orow[8 * g + 4 * hi] = h4a;
            *(half4*)&orow[32 + 8 * g + 4 * hi] = h4b;
        }
        if (!hi) lpart[quarter * 65536 + (b * 16 + h) * 2048 + tok] = lrun;
    } else {
        const float inv = __builtin_amdgcn_rcpf(lrun);
        _Float16* orow = out + (size_t)(b * 2048 + tok) * 1024 + h * 64;
#pragma unroll
        for (int g = 0; g < 4; g++) {
            half4 h4a, h4b;
#pragma unroll
            for (int j = 0; j < 4; j++) {
                h4a[j] = (_Float16)(o0[4 * g + j] * inv);
                h4b[j] = (_Float16)(o1[4 * g + j] * inv);
            }
            *(half4*)&orow[8 * g + 4 * hi] = h4a;
            *(half4*)&orow[32 + 8 * g + 4 * hi] = h4b;
        }
    }
}

// ---------------------------------------------------------------- split-KV merge: attnh = (sum numerators)/(sum l)
__global__ __launch_bounds__(256) void merge_attn(const _Float16* __restrict__ onum,
                                                  const float* __restrict__ lpart,
                                                  _Float16* __restrict__ attnh) {
    const int i = blockIdx.x * 256 + threadIdx.x;  // [0, 524288) half8 units
    const int tokb = i >> 7;                       // b*2048 + tok
    const int c0 = (i & 127) * 8;
    const int h = c0 >> 6;
    const int bb = tokb >> 11, tok = tokb & 2047;
    const int li = (bb * 16 + h) * 2048 + tok;
    float lt = lpart[li] + lpart[65536 + li] + lpart[131072 + li] + lpart[196608 + li];
    float inv = __builtin_amdgcn_rcpf(lt);
    float acc[8] = {};
#pragma unroll
    for (int q = 0; q < 4; q++) {
        half8 v = *(const half8*)&onum[(size_t)q * 4194304 + (size_t)tokb * 1024 + c0];
#pragma unroll
        for (int j = 0; j < 8; j++) acc[j] += (float)v[j];
    }
    half8 o;
#pragma unroll
    for (int j = 0; j < 8; j++) o[j] = (_Float16)(acc[j] * inv);
    *(half8*)&attnh[(size_t)tokb * 1024 + c0] = o;
}

// ---------------------------------------------------------------- launch
extern "C" void kernel_launch(void* const* d_in, const int* in_sizes, int n_in,
                              void* d_out, int out_size, void* d_ws, size_t ws_size,
                              hipStream_t stream) {
    const float* x = (const float*)d_in[0];
    const float* w_qkv = (const float*)d_in[1];
    const float* b_qkv = (const float*)d_in[2];
    const float* q_gamma = (const float*)d_in[3];
    const float* q_beta = (const float*)d_in[4];
    const float* k_gamma = (const float*)d_in[5];
    const float* k_beta = (const float*)d_in[6];
    const float* w_proj = (const float*)d_in[7];
    const float* b_proj = (const float*)d_in[8];

    char* ws = (char*)d_ws;
    _Float16* xh = (_Float16*)(ws + 0);             // 4096*1024
    _Float16* wqkvh = (_Float16*)(ws + 8388608);    // 3072*1024
    _Float16* wprojh = (_Float16*)(ws + 14680064);  // 1024*1024
    _Float16* qkvh = (_Float16*)(ws + 16777216);    // 3*2*16*2048*64
    _Float16* attnh = (_Float16*)(ws + 41943040);   // 4096*1024
    _Float16* onum = (_Float16*)(ws + 50331648);    // 4 * 4096*1024 fp16 = 32 MB
    float* lp = (float*)(ws + 83886080);            // 4 * 65536 f32 = 1 MB
    const bool split = ws_size >= 84934656;

    cvt_all<<<4096, 256, 0, stream>>>(x, w_qkv, w_proj, xh, wqkvh, wprojh);

    gemm_nt<2, 4, 0><<<dim3(64, 24), 256, 0, stream>>>(xh, wqkvh, b_qkv, (void*)qkvh, 1024,
                                                       q_gamma, q_beta, k_gamma, k_beta);

    if (split) {
        attn_kernel<4><<<2048, 256, 0, stream>>>(qkvh, onum, lp);
        merge_attn<<<2048, 256, 0, stream>>>(onum, lp, attnh);
    } else {
        attn_kernel<1><<<512, 256, 0, stream>>>(qkvh, attnh, nullptr);
    }

    gemm_nt<2, 2, 1><<<dim3(64, 16), 256, 0, stream>>>(attnh, wprojh, b_proj, d_out, 1024,
                                                       nullptr, nullptr, nullptr, nullptr);
}

// Round 7
// 222.851 us; speedup vs baseline: 1.1005x; 1.0089x over previous
//
#include <hip/hip_runtime.h>

typedef _Float16 half8 __attribute__((ext_vector_type(8)));
typedef _Float16 half4 __attribute__((ext_vector_type(4)));
typedef float f32x4 __attribute__((ext_vector_type(4)));
typedef float f32x16 __attribute__((ext_vector_type(16)));
typedef unsigned int uint;
typedef uint uint2v __attribute__((ext_vector_type(2)));
typedef uint uint4v __attribute__((ext_vector_type(4)));

#define MFMA16(a, b, c) __builtin_amdgcn_mfma_f32_16x16x32_f16((a), (b), (c), 0, 0, 0)
#define MFMA32(a, b, c) __builtin_amdgcn_mfma_f32_32x32x16_f16((a), (b), (c), 0, 0, 0)

// async global->LDS, 16B per lane, dest = wave-uniform base + lane*16
#define GLOAD16(g, l)                                            \
    __builtin_amdgcn_global_load_lds(                            \
        (const __attribute__((address_space(1))) void*)(g),      \
        (__attribute__((address_space(3))) void*)(l), 16, 0, 0)

// B=2, N=2048, C=1024, H=16, D=64; M = B*N = 4096 tokens.
// qkv buffer layout: [s][b][h][n][d], s-stride = 2*16*2048*64 = 4194304 elems.
// q rows are stored LN'd AND pre-scaled by 0.125*log2(e) (folded into gemm1 epilogue, f32).

// ---------------------------------------------------------------- fused fp32 -> fp16 (x, w_qkv, w_proj)
__global__ __launch_bounds__(256) void cvt_all(const float* __restrict__ x,
                                               const float* __restrict__ wq,
                                               const float* __restrict__ wp,
                                               _Float16* __restrict__ xh,
                                               _Float16* __restrict__ wqh,
                                               _Float16* __restrict__ wph) {
    int i = blockIdx.x * 256 + threadIdx.x;  // 1,048,576 half8 units
    const float* src;
    _Float16* dst;
    int off;
    if (i < 524288) { src = x; dst = xh; off = i; }
    else if (i < 917504) { src = wq; dst = wqh; off = i - 524288; }
    else { src = wp; dst = wph; off = i - 917504; }
    const float4* p = reinterpret_cast<const float4*>(src) + 2 * (size_t)off;
    float4 a = p[0], b = p[1];
    half8 o;
    o[0] = (_Float16)a.x; o[1] = (_Float16)a.y; o[2] = (_Float16)a.z; o[3] = (_Float16)a.w;
    o[4] = (_Float16)b.x; o[5] = (_Float16)b.y; o[6] = (_Float16)b.z; o[7] = (_Float16)b.w;
    reinterpret_cast<half8*>(dst)[off] = o;
}

// ---------------------------------------------------------------- GEMM1: 8-phase 256x256 (T2+T3+T4+T5)
// 512 thr = 8 waves (2M x 4N); per-wave C = 128x64. BK=64, 16 K-tiles, 8 iters x 8 phases.
// LDS 128KB: [buf][half][r][64][64] for A and B. A-half h = rows {h*64..+63} U {128+h*64..+63}
// (r = wm block); B-half h = rows {h*128..+127} (r = 64-row block). Counted vmcnt(2) at ph4/ph8 only.
// Epilogue: fused per-head LayerNorm on q,k + scatter (q scaled by 0.125*log2e).
__global__ __launch_bounds__(512) void gemm1_8ph(const _Float16* __restrict__ A,
                                                 const _Float16* __restrict__ W,
                                                 const float* __restrict__ bias,
                                                 _Float16* __restrict__ qkv,
                                                 const float* __restrict__ qg,
                                                 const float* __restrict__ qb,
                                                 const float* __restrict__ kg,
                                                 const float* __restrict__ kb) {
    constexpr int K = 1024;
    __shared__ __align__(16) _Float16 AL[2][2][2][64][64];
    __shared__ __align__(16) _Float16 BL[2][2][2][64][64];
    const int tid = threadIdx.x, l = tid & 63, w = tid >> 6;
    const int wm = w >> 2, wn = w & 3;
    const int lin = blockIdx.x + (blockIdx.y << 4);  // gridDim.x == 16
    const int wg = (lin & 7) * 24 + (lin >> 3);      // bijective XCD swizzle (192 wgs)
    const int bm = (wg & 15) * 256, bn = (wg >> 4) * 256;
    const int srow = l >> 3, sch = (l & 7) ^ (srow & 7);  // pre-swizzled source chunk
    const int rowA = l & 15;

    auto stageA = [&](int t, int h) {
        const int buf = t & 1;
#pragma unroll
        for (int r = 0; r < 2; r++) {
            int absrow = r * 128 + h * 64 + w * 8 + srow;
            GLOAD16(A + (size_t)(bm + absrow) * K + t * 64 + 8 * sch, &AL[buf][h][r][w * 8][0]);
        }
    };
    auto stageB = [&](int t, int h) {
        const int buf = t & 1;
#pragma unroll
        for (int r = 0; r < 2; r++) {
            int absrow = h * 128 + r * 64 + w * 8 + srow;
            GLOAD16(W + (size_t)(bn + absrow) * K + t * 64 + 8 * sch, &BL[buf][h][r][w * 8][0]);
        }
    };

    f32x4 acc[8][4] = {};

    // prologue: tile0 full + tile1's A-h0; counted wait leaves A(1,0) in flight
    stageA(0, 0); stageA(0, 1); stageB(0, 0); stageB(0, 1); stageA(1, 0);
    asm volatile("s_waitcnt vmcnt(2)" ::: "memory");
    __builtin_amdgcn_s_barrier();

#define PH(BUF, QM, QK, STAGE, VM)                                                        \
    {                                                                                     \
        half8 af[4], wf[4];                                                               \
        const int kc = (((QK) * 4 + (l >> 4)) ^ (l & 7)) * 8;                             \
        _Pragma("unroll") for (int f = 0; f < 4; f++)                                     \
            af[f] = *(const half8*)&AL[BUF][QM][wm][f * 16 + rowA][kc];                   \
        _Pragma("unroll") for (int f = 0; f < 4; f++)                                     \
            wf[f] = *(const half8*)&BL[BUF][wn >> 1][wn & 1][f * 16 + rowA][kc];          \
        STAGE;                                                                            \
        __builtin_amdgcn_s_barrier();                                                     \
        asm volatile("s_waitcnt lgkmcnt(0)" ::: "memory");                                \
        __builtin_amdgcn_sched_barrier(0);                                                \
        __builtin_amdgcn_s_setprio(1);                                                    \
        _Pragma("unroll") for (int mf = 0; mf < 4; mf++)                                  \
            _Pragma("unroll") for (int nf = 0; nf < 4; nf++)                              \
                acc[(QM) * 4 + mf][nf] = MFMA16(af[mf], wf[nf], acc[(QM) * 4 + mf][nf]);  \
        __builtin_amdgcn_s_setprio(0);                                                    \
        if (VM) asm volatile("s_waitcnt vmcnt(2)" ::: "memory");                          \
        __builtin_amdgcn_s_barrier();                                                     \
    }

    for (int i = 0; i < 8; ++i) {
        const int t1 = 2 * i + 1;
        const int s2 = (i < 7) ? 2 * i + 2 : 14;  // clamped refetch, never read
        const int s3 = (i < 7) ? 2 * i + 3 : 15;
        PH(0, 0, 0, stageA(t1, 1), 0)  // ph1
        PH(0, 1, 0, stageB(t1, 0), 0)  // ph2
        PH(0, 0, 1, stageB(t1, 1), 0)  // ph3
        PH(0, 1, 1, stageA(s2, 0), 1)  // ph4  vmcnt(2)
        PH(1, 0, 0, stageA(s2, 1), 0)  // ph5
        PH(1, 1, 0, stageB(s2, 0), 0)  // ph6
        PH(1, 0, 1, stageB(s2, 1), 0)  // ph7
        PH(1, 1, 1, stageA(s3, 0), 1)  // ph8  vmcnt(2)
    }
#undef PH

    // ---- epilogue: fused LN + scatter to qkv [s][b][h][n][d]
    const int ncol = bn + wn * 64;  // one (s, head) d-window
    const int s = ncol >> 10;
    const int hh = (ncol >> 6) & 15;
    const float* gam = (s == 0) ? qg : kg;
    const float* bet = (s == 0) ? qb : kb;
    float ga[4], be[4];
    if (s < 2) {
#pragma unroll
        for (int nf = 0; nf < 4; nf++) {
            int d = nf * 16 + rowA;
            ga[nf] = gam[d];
            be[nf] = bet[d];
        }
    }
    const float cs = (s == 0) ? 0.18033688f : 1.f;
#pragma unroll
    for (int mfa = 0; mfa < 8; mfa++)
#pragma unroll
        for (int r = 0; r < 4; r++) {
            float v[4];
            float sm = 0.f, s2s = 0.f;
#pragma unroll
            for (int nf = 0; nf < 4; nf++) {
                v[nf] = acc[mfa][nf][r] + bias[ncol + nf * 16 + rowA];
                sm += v[nf];
                s2s += v[nf] * v[nf];
            }
            int m = bm + wm * 128 + mfa * 16 + (l >> 4) * 4 + r;
            int b = m >> 11, nn = m & 2047;
            _Float16* dst = qkv + (size_t)((((s * 2 + b) * 16 + hh) * 2048 + nn) << 6);
            if (s < 2) {
#pragma unroll
                for (int off = 1; off < 16; off <<= 1) {
                    sm += __shfl_xor(sm, off);
                    s2s += __shfl_xor(s2s, off);
                }
                float mean = sm * (1.f / 64.f);
                float var = s2s * (1.f / 64.f) - mean * mean;
                float rs = rsqrtf(var + 1e-5f) * cs;
#pragma unroll
                for (int nf = 0; nf < 4; nf++)
                    dst[nf * 16 + rowA] = (_Float16)((v[nf] - mean) * rs * ga[nf] + be[nf] * cs);
            } else {
#pragma unroll
                for (int nf = 0; nf < 4; nf++)
                    dst[nf * 16 + rowA] = (_Float16)v[nf];
            }
        }
}

// ---------------------------------------------------------------- GEMM (NT), 2-phase pipelined (gemm2)
template <int MT, int NT>
__global__ __launch_bounds__(256) void gemm_nt(const _Float16* __restrict__ A,
                                               const _Float16* __restrict__ W,
                                               const float* __restrict__ bias,
                                               float* __restrict__ Cout, int K) {
    constexpr int TM = MT * 32;
    constexpr int TN = NT * 32;
    __shared__ __align__(16) _Float16 Al[2][TM * 64];
    __shared__ __align__(16) _Float16 Wl[2][TN * 64];
    const int tid = threadIdx.x, l = tid & 63, w = tid >> 6;
    const int lin = blockIdx.x + (blockIdx.y << 6);  // gridDim.x == 64
    const int nwg = gridDim.x * gridDim.y;
    const int wg = (lin & 7) * (nwg >> 3) + (lin >> 3);
    const int bm = (wg & 63) * TM, bn = (wg >> 6) * TN;
    const int wr = (w >> 1) * (MT * 16), wc = (w & 1) * (NT * 16);
    const int srow = l >> 3;
    const int schunk = (l & 7) ^ srow;

    const _Float16* Ag = A + (size_t)(bm + (TM / 4) * w + srow) * K + 8 * schunk;
    const _Float16* Wg = W + (size_t)(bn + (TN / 4) * w + srow) * K + 8 * schunk;
    const int rswz = (l & 7) << 3;
    const int nk = K >> 6;

    auto stage = [&](int t, int buf) {
        const int kt = t << 6;
#pragma unroll
        for (int i = 0; i < MT; i++)
            GLOAD16(Ag + (size_t)(8 * i) * K + kt, &Al[buf][((TM / 4) * w + 8 * i) * 64]);
#pragma unroll
        for (int i = 0; i < NT; i++)
            GLOAD16(Wg + (size_t)(8 * i) * K + kt, &Wl[buf][((TN / 4) * w + 8 * i) * 64]);
    };

    f32x4 acc[MT][NT] = {};
    stage(0, 0);
    __syncthreads();
    for (int t = 0; t < nk; ++t) {
        const int cur = t & 1;
        if (t + 1 < nk) stage(t + 1, cur ^ 1);
#pragma unroll
        for (int ks = 0; ks < 2; ks++) {
            const int koff = (ks * 32 + (l >> 4) * 8) ^ rswz;
            half8 af[MT], wf[NT];
#pragma unroll
            for (int i = 0; i < MT; i++)
                af[i] = *(const half8*)&Al[cur][(wr + i * 16 + (l & 15)) * 64 + koff];
#pragma unroll
            for (int i = 0; i < NT; i++)
                wf[i] = *(const half8*)&Wl[cur][(wc + i * 16 + (l & 15)) * 64 + koff];
            __builtin_amdgcn_s_setprio(1);
#pragma unroll
            for (int mt = 0; mt < MT; mt++)
#pragma unroll
                for (int nt = 0; nt < NT; nt++)
                    acc[mt][nt] = MFMA16(af[mt], wf[nt], acc[mt][nt]);
            __builtin_amdgcn_s_setprio(0);
        }
        __syncthreads();
    }
#pragma unroll
    for (int mt = 0; mt < MT; mt++)
#pragma unroll
        for (int nt = 0; nt < NT; nt++)
#pragma unroll
            for (int r = 0; r < 4; r++) {
                int m = bm + wr + mt * 16 + (l >> 4) * 4 + r;
                int n = bn + wc + nt * 16 + (l & 15);
                Cout[(size_t)m * 1024 + n] = acc[mt][nt][r] + bias[n];
            }
}

// ---------------------------------------------------------------- flash attention, swapped-QK^T 32x32
// SPLIT=4: grid 2048, 8 iters, fp16 numerator partials + f32 l partials (exact-sum merge).
// No online max (q pre-scaled by 0.125*log2e => p = 2^s' <= 2980 fits fp16).
// Two-half score pipeline + no early V-regs => fits the 128-reg class without spill.
template <int SPLIT>
__global__ __launch_bounds__(256, 4) void attn_kernel(const _Float16* __restrict__ qkv,
                                                      _Float16* __restrict__ out,
                                                      float* __restrict__ lpart) {
    const int tid = threadIdx.x;
    const int l = tid & 63, w = tid >> 6;
    const int l31 = l & 31, hi = l >> 5;
    const int bid = blockIdx.x;
    const int nwg = 512 * SPLIT;
    const int wg = (bid & 7) * (nwg >> 3) + (bid >> 3);
    int head, qt, quarter;
    if (SPLIT == 4) { head = wg >> 6; qt = (wg >> 2) & 15; quarter = wg & 3; }
    else            { head = wg >> 4; qt = wg & 15;        quarter = 0; }
    const int b = head >> 4, h = head & 15;
    const size_t hstride = (size_t)2048 * 64;
    const _Float16* Q = qkv + (size_t)((0 + b) * 16 + h) * hstride;
    const _Float16* Kp = qkv + (size_t)((2 + b) * 16 + h) * hstride + (size_t)quarter * 512 * 64;
    const _Float16* Vp = qkv + (size_t)((4 + b) * 16 + h) * hstride + (size_t)quarter * 512 * 64;
    const int NIT = (SPLIT == 4) ? 8 : 32;

    __shared__ __align__(16) _Float16 Kl[2][64 * 64];  // [k][d], chunk ^= (k&7)
    __shared__ __align__(16) _Float16 Vt[2][64 * 64];  // [d][k], slot ^= (d&7)^((d>>3)&7)

    const int r0q = qt * 128 + w * 32;
    half8 qf[4];
    {
        const _Float16* Qrow = Q + (size_t)(r0q + l31) * 64 + 8 * hi;
#pragma unroll
        for (int dk = 0; dk < 4; dk++) qf[dk] = *(const half8*)&Qrow[16 * dk];
    }

    const int srow = l >> 3, sch = l & 7;
    auto stageK = [&](int it, _Float16* dst) {
#pragma unroll
        for (int t = 0; t < 2; t++) {
            int r0 = 16 * w + 8 * t;
            const _Float16* g = Kp + (size_t)(it * 64 + r0 + srow) * 64 + 8 * (sch ^ srow);
            GLOAD16(g, &dst[r0 * 64]);
        }
    };
    // load V 16 rows + transpose-scatter immediately (no long-lived regs)
    auto loadScatterV = [&](int it, _Float16* dst) {
        const _Float16* g = Vp + (size_t)(it * 64 + 16 * w + srow) * 64 + 8 * sch;
        half8 v0 = *(const half8*)g;
        half8 v1 = *(const half8*)(g + 8 * 64);
        const int j0 = 16 * w + srow;
        const int d0 = 8 * sch;
#pragma unroll
        for (int i = 0; i < 8; i++) {
            const int sw = (i ^ sch) << 3;
            dst[(d0 + i) * 64 + (j0 ^ sw)] = v0[i];
            dst[(d0 + i) * 64 + ((j0 + 8) ^ sw)] = v1[i];
        }
    };

    float lrun = 0.f;
    f32x16 o0 = {}, o1 = {};

    stageK(0, Kl[0]);
    loadScatterV(0, Vt[0]);
    __syncthreads();

    const int kswz = (l31 & 7) << 3;
    const int vswz0 = ((l31 & 7) ^ (l31 >> 3)) << 3;
    const int vswz1 = vswz0 ^ (4 << 3);

    for (int it = 0; it < NIT; ++it) {
        const int cur = it & 1;
        const _Float16* Kc = Kl[cur];
        const _Float16* Vc = Vt[cur];
        if (it + 1 < NIT) stageK(it + 1, Kl[cur ^ 1]);  // async across compute

#pragma unroll
        for (int hf = 0; hf < 2; hf++) {
            f32x16 st = {};
#pragma unroll
            for (int dk = 0; dk < 4; dk++) {
                const int colr = 16 * dk + 8 * hi;
                half8 kf = *(const half8*)&Kc[(hf * 32 + l31) * 64 + (colr ^ kswz)];
                __builtin_amdgcn_s_setprio(1);
                st = MFMA32(kf, qf[dk], st);
                __builtin_amdgcn_s_setprio(0);
            }
#pragma unroll
            for (int r = 0; r < 16; r++) st[r] = exp2f(st[r]);
            lrun += (((st[0] + st[1]) + (st[2] + st[3])) +
                     ((st[4] + st[5]) + (st[6] + st[7]))) +
                    (((st[8] + st[9]) + (st[10] + st[11])) +
                     ((st[12] + st[13]) + (st[14] + st[15])));

#pragma unroll
            for (int cc = 0; cc < 2; cc++) {
                const int c = 2 * hf + cc;
                uint pk0 = __builtin_bit_cast(uint, __builtin_amdgcn_cvt_pkrtz(st[cc * 8 + 0], st[cc * 8 + 1]));
                uint pk1 = __builtin_bit_cast(uint, __builtin_amdgcn_cvt_pkrtz(st[cc * 8 + 2], st[cc * 8 + 3]));
                uint pk2 = __builtin_bit_cast(uint, __builtin_amdgcn_cvt_pkrtz(st[cc * 8 + 4], st[cc * 8 + 5]));
                uint pk3 = __builtin_bit_cast(uint, __builtin_amdgcn_cvt_pkrtz(st[cc * 8 + 6], st[cc * 8 + 7]));
                uint2v s02 = __builtin_amdgcn_permlane32_swap(pk0, pk2, false, false);
                uint2v s13 = __builtin_amdgcn_permlane32_swap(pk1, pk3, false, false);
                uint4v fu = {s02.x, s13.x, s02.y, s13.y};
                half8 pfrag = __builtin_bit_cast(half8, fu);
                const int colc = 16 * c + 8 * hi;
                half8 vf0 = *(const half8*)&Vc[l31 * 64 + (colc ^ vswz0)];
                half8 vf1 = *(const half8*)&Vc[(32 + l31) * 64 + (colc ^ vswz1)];
                __builtin_amdgcn_s_setprio(1);
                o0 = MFMA32(vf0, pfrag, o0);
                o1 = MFMA32(vf1, pfrag, o1);
                __builtin_amdgcn_s_setprio(0);
            }
        }

        if (it + 1 < NIT) loadScatterV(it + 1, Vt[cur ^ 1]);
        __syncthreads();
    }

    lrun += __shfl_xor(lrun, 32);
    const int tok = r0q + l31;
    if (SPLIT == 4) {
        _Float16* orow = out + (size_t)quarter * 4194304 + (size_t)(b * 2048 + tok) * 1024 + h * 64;
#pragma unroll
        for (int g = 0; g < 4; g++) {
            half4 h4a, h4b;
#pragma unroll
            for (int j = 0; j < 4; j++) {
                h4a[j] = (_Float16)o0[4 * g + j];
                h4b[j] = (_Float16)o1[4 * g + j];
            }
            *(half4*)&orow[8 * g + 4 * hi] = h4a;
            *(half4*)&orow[32 + 8 * g + 4 * hi] = h4b;
        }
        if (!hi) lpart[quarter * 65536 + (b * 16 + h) * 2048 + tok] = lrun;
    } else {
        const float inv = __builtin_amdgcn_rcpf(lrun);
        _Float16* orow = out + (size_t)(b * 2048 + tok) * 1024 + h * 64;
#pragma unroll
        for (int g = 0; g < 4; g++) {
            half4 h4a, h4b;
#pragma unroll
            for (int j = 0; j < 4; j++) {
                h4a[j] = (_Float16)(o0[4 * g + j] * inv);
                h4b[j] = (_Float16)(o1[4 * g + j] * inv);
            }
            *(half4*)&orow[8 * g + 4 * hi] = h4a;
            *(half4*)&orow[32 + 8 * g + 4 * hi] = h4b;
        }
    }
}

// ---------------------------------------------------------------- split-KV merge
__global__ __launch_bounds__(256) void merge_attn(const _Float16* __restrict__ onum,
                                                  const float* __restrict__ lpart,
                                                  _Float16* __restrict__ attnh) {
    const int i = blockIdx.x * 256 + threadIdx.x;
    const int tokb = i >> 7;
    const int c0 = (i & 127) * 8;
    const int h = c0 >> 6;
    const int bb = tokb >> 11, tok = tokb & 2047;
    const int li = (bb * 16 + h) * 2048 + tok;
    float lt = lpart[li] + lpart[65536 + li] + lpart[131072 + li] + lpart[196608 + li];
    float inv = __builtin_amdgcn_rcpf(lt);
    float acc[8] = {};
#pragma unroll
    for (int q = 0; q < 4; q++) {
        half8 v = *(const half8*)&onum[(size_t)q * 4194304 + (size_t)tokb * 1024 + c0];
#pragma unroll
        for (int j = 0; j < 8; j++) acc[j] += (float)v[j];
    }
    half8 o;
#pragma unroll
    for (int j = 0; j < 8; j++) o[j] = (_Float16)(acc[j] * inv);
    *(half8*)&attnh[(size_t)tokb * 1024 + c0] = o;
}

// ---------------------------------------------------------------- launch
extern "C" void kernel_launch(void* const* d_in, const int* in_sizes, int n_in,
                              void* d_out, int out_size, void* d_ws, size_t ws_size,
                              hipStream_t stream) {
    const float* x = (const float*)d_in[0];
    const float* w_qkv = (const float*)d_in[1];
    const float* b_qkv = (const float*)d_in[2];
    const float* q_gamma = (const float*)d_in[3];
    const float* q_beta = (const float*)d_in[4];
    const float* k_gamma = (const float*)d_in[5];
    const float* k_beta = (const float*)d_in[6];
    const float* w_proj = (const float*)d_in[7];
    const float* b_proj = (const float*)d_in[8];

    char* ws = (char*)d_ws;
    _Float16* xh = (_Float16*)(ws + 0);             // 4096*1024
    _Float16* wqkvh = (_Float16*)(ws + 8388608);    // 3072*1024
    _Float16* wprojh = (_Float16*)(ws + 14680064);  // 1024*1024
    _Float16* qkvh = (_Float16*)(ws + 16777216);    // 3*2*16*2048*64
    _Float16* attnh = (_Float16*)(ws + 41943040);   // 4096*1024
    _Float16* onum = (_Float16*)(ws + 50331648);    // 4 * 4096*1024 fp16 = 32 MB
    float* lp = (float*)(ws + 83886080);            // 4 * 65536 f32 = 1 MB
    const bool split = ws_size >= 84934656;

    cvt_all<<<4096, 256, 0, stream>>>(x, w_qkv, w_proj, xh, wqkvh, wprojh);

    gemm1_8ph<<<dim3(16, 12), 512, 0, stream>>>(xh, wqkvh, b_qkv, qkvh,
                                                q_gamma, q_beta, k_gamma, k_beta);

    if (split) {
        attn_kernel<4><<<2048, 256, 0, stream>>>(qkvh, onum, lp);
        merge_attn<<<2048, 256, 0, stream>>>(onum, lp, attnh);
    } else {
        attn_kernel<1><<<512, 256, 0, stream>>>(qkvh, attnh, nullptr);
    }

    gemm_nt<2, 2><<<dim3(64, 16), 256, 0, stream>>>(attnh, wprojh, b_proj, (float*)d_out, 1024);
}

// Round 8
// 208.469 us; speedup vs baseline: 1.1764x; 1.0690x over previous
//
#include <hip/hip_runtime.h>

typedef _Float16 half8 __attribute__((ext_vector_type(8)));
typedef _Float16 half4 __attribute__((ext_vector_type(4)));
typedef float f32x4 __attribute__((ext_vector_type(4)));
typedef float f32x16 __attribute__((ext_vector_type(16)));
typedef unsigned int uint;
typedef uint uint2v __attribute__((ext_vector_type(2)));
typedef uint uint4v __attribute__((ext_vector_type(4)));

#define MFMA16(a, b, c) __builtin_amdgcn_mfma_f32_16x16x32_f16((a), (b), (c), 0, 0, 0)
#define MFMA32(a, b, c) __builtin_amdgcn_mfma_f32_32x32x16_f16((a), (b), (c), 0, 0, 0)

// async global->LDS, 16B per lane, dest = wave-uniform base + lane*16
#define GLOAD16(g, l)                                            \
    __builtin_amdgcn_global_load_lds(                            \
        (const __attribute__((address_space(1))) void*)(g),      \
        (__attribute__((address_space(3))) void*)(l), 16, 0, 0)

// B=2, N=2048, C=1024, H=16, D=64; M = B*N = 4096 tokens.
// qkv buffer layout: [s][b][h][n][d], s-stride = 2*16*2048*64 = 4194304 elems.
// q rows are stored LN'd AND pre-scaled by 0.125*log2(e) (folded into gemm1 epilogue, f32).

// ---------------------------------------------------------------- fused fp32 -> fp16 (x, w_qkv, w_proj)
__global__ __launch_bounds__(256) void cvt_all(const float* __restrict__ x,
                                               const float* __restrict__ wq,
                                               const float* __restrict__ wp,
                                               _Float16* __restrict__ xh,
                                               _Float16* __restrict__ wqh,
                                               _Float16* __restrict__ wph) {
    int i = blockIdx.x * 256 + threadIdx.x;  // 1,048,576 half8 units
    const float* src;
    _Float16* dst;
    int off;
    if (i < 524288) { src = x; dst = xh; off = i; }
    else if (i < 917504) { src = wq; dst = wqh; off = i - 524288; }
    else { src = wp; dst = wph; off = i - 917504; }
    const float4* p = reinterpret_cast<const float4*>(src) + 2 * (size_t)off;
    float4 a = p[0], b = p[1];
    half8 o;
    o[0] = (_Float16)a.x; o[1] = (_Float16)a.y; o[2] = (_Float16)a.z; o[3] = (_Float16)a.w;
    o[4] = (_Float16)b.x; o[5] = (_Float16)b.y; o[6] = (_Float16)b.z; o[7] = (_Float16)b.w;
    reinterpret_cast<half8*>(dst)[off] = o;
}

// ---------------------------------------------------------------- GEMM (NT), m97 single-buffered
// (MT*32) x (NT*32) tile, BK=64, global_load_lds staging, XOR-swizzled linear LDS.
// XCD supertiling: wg-chunk per XCD = rectangle of (2^RIML2) m-tiles x RIN n-tiles so the
// chunk's A+B panels fit the 4MB per-XCD L2 (locality, not schedule, limits these GEMMs).
// XCDs arranged 4 (m) x 2 (n). Loop: sync; stage(t); sync; compute(t)  [R3 structure].
// EPI 0 (NT=4): fused per-head LayerNorm on q,k + scatter (q scaled 0.125*log2e).
// EPI 1: fp32 out [m][n].
template <int MT, int NT, int EPI, int RIML2, int RIN>
__global__ __launch_bounds__(256) void gemm_nt(const _Float16* __restrict__ A,
                                               const _Float16* __restrict__ W,
                                               const float* __restrict__ bias,
                                               void* __restrict__ Cout, int K,
                                               const float* __restrict__ qg,
                                               const float* __restrict__ qb,
                                               const float* __restrict__ kg,
                                               const float* __restrict__ kb) {
    constexpr int TM = MT * 32;
    constexpr int TN = NT * 32;
    __shared__ __align__(16) _Float16 Al[TM * 64];
    __shared__ __align__(16) _Float16 Wl[TN * 64];
    const int tid = threadIdx.x, l = tid & 63, w = tid >> 6;
    const int lin = blockIdx.x + blockIdx.y * gridDim.x;
    const int xcd = lin & 7, idx = lin >> 3;
    const int im = idx & ((1 << RIML2) - 1), in = idx >> RIML2;
    const int bm = ((xcd & 3) * (1 << RIML2) + im) * TM;
    const int bn = ((xcd >> 2) * RIN + in) * TN;
    const int wr = (w >> 1) * (MT * 16), wc = (w & 1) * (NT * 16);
    const int srow = l >> 3;
    const int schunk = (l & 7) ^ srow;     // pre-swizzled source chunk (rule #21)
    const int rswz = (l & 7) << 3;         // read-side XOR (halfs)

    const _Float16* Ag = A + (size_t)(bm + (TM / 4) * w + srow) * K + 8 * schunk;
    const _Float16* Wg = W + (size_t)(bn + (TN / 4) * w + srow) * K + 8 * schunk;
    const int nk = K >> 6;

    f32x4 acc[MT][NT] = {};
    for (int t = 0; t < nk; ++t) {
        const int kt = t << 6;
        __syncthreads();
#pragma unroll
        for (int i = 0; i < MT; i++)
            GLOAD16(Ag + (size_t)(8 * i) * K + kt, &Al[((TM / 4) * w + 8 * i) * 64]);
#pragma unroll
        for (int i = 0; i < NT; i++)
            GLOAD16(Wg + (size_t)(8 * i) * K + kt, &Wl[((TN / 4) * w + 8 * i) * 64]);
        __syncthreads();
#pragma unroll
        for (int ks = 0; ks < 2; ks++) {
            const int koff = (ks * 32 + (l >> 4) * 8) ^ rswz;
            half8 af[MT], wf[NT];
#pragma unroll
            for (int i = 0; i < MT; i++)
                af[i] = *(const half8*)&Al[(wr + i * 16 + (l & 15)) * 64 + koff];
#pragma unroll
            for (int i = 0; i < NT; i++)
                wf[i] = *(const half8*)&Wl[(wc + i * 16 + (l & 15)) * 64 + koff];
            __builtin_amdgcn_s_setprio(1);
#pragma unroll
            for (int mt = 0; mt < MT; mt++)
#pragma unroll
                for (int nt = 0; nt < NT; nt++)
                    acc[mt][nt] = MFMA16(af[mt], wf[nt], acc[mt][nt]);
            __builtin_amdgcn_s_setprio(0);
        }
    }

    if (EPI == 0) {
        const int ncol = bn + wc;          // 64-aligned -> exactly one (s, head) d-window
        const int s = ncol >> 10;
        const int hh = (ncol >> 6) & 15;
        const float* gam = (s == 0) ? qg : kg;
        const float* bet = (s == 0) ? qb : kb;
        float ga[4], be[4];
        if (s < 2) {
#pragma unroll
            for (int nt = 0; nt < 4; nt++) {
                int d = nt * 16 + (l & 15);
                ga[nt] = gam[d];
                be[nt] = bet[d];
            }
        }
        const float cs = (s == 0) ? 0.18033688f : 1.f;  // 0.125*log2(e) folded into q
#pragma unroll
        for (int mt = 0; mt < MT; mt++)
#pragma unroll
            for (int r = 0; r < 4; r++) {
                float v[4];
                float sm = 0.f, s2 = 0.f;
#pragma unroll
                for (int nt = 0; nt < 4; nt++) {
                    v[nt] = acc[mt][nt][r] + bias[ncol + nt * 16 + (l & 15)];
                    sm += v[nt];
                    s2 += v[nt] * v[nt];
                }
                int m = bm + wr + mt * 16 + (l >> 4) * 4 + r;
                int b = m >> 11, nn = m & 2047;
                _Float16* dst = (_Float16*)Cout +
                    (size_t)((((s * 2 + b) * 16 + hh) * 2048 + nn) << 6);
                if (s < 2) {
#pragma unroll
                    for (int off = 1; off < 16; off <<= 1) {
                        sm += __shfl_xor(sm, off);
                        s2 += __shfl_xor(s2, off);
                    }
                    float mean = sm * (1.f / 64.f);
                    float var = s2 * (1.f / 64.f) - mean * mean;
                    float rs = rsqrtf(var + 1e-5f) * cs;
#pragma unroll
                    for (int nt = 0; nt < 4; nt++) {
                        int d = nt * 16 + (l & 15);
                        dst[d] = (_Float16)((v[nt] - mean) * rs * ga[nt] + be[nt] * cs);
                    }
                } else {
#pragma unroll
                    for (int nt = 0; nt < 4; nt++)
                        dst[nt * 16 + (l & 15)] = (_Float16)v[nt];
                }
            }
    } else {
#pragma unroll
        for (int mt = 0; mt < MT; mt++)
#pragma unroll
            for (int nt = 0; nt < NT; nt++)
#pragma unroll
                for (int r = 0; r < 4; r++) {
                    int m = bm + wr + mt * 16 + (l >> 4) * 4 + r;
                    int n = bn + wc + nt * 16 + (l & 15);
                    ((float*)Cout)[(size_t)m * 1024 + n] = acc[mt][nt][r] + bias[n];
                }
    }
}

// ---------------------------------------------------------------- flash attention, swapped-QK^T 32x32
// SPLIT=2: grid 1024 (= exact 4 blocks/CU residency fill), 16 iters, fp16 numerator partials +
// f32 l partials (no-max softmax => partials merge by plain summation).
// No online max (q pre-scaled by 0.125*log2e => p = 2^s' <= 2980 fits fp16).
// Two-half score pipeline keeps live regs in the 128 class (4 waves/SIMD, no spill).
template <int SPLIT>
__global__ __launch_bounds__(256, 4) void attn_kernel(const _Float16* __restrict__ qkv,
                                                      _Float16* __restrict__ out,
                                                      float* __restrict__ lpart) {
    constexpr int LS = (SPLIT == 4) ? 2 : (SPLIT == 2) ? 1 : 0;
    const int tid = threadIdx.x;
    const int l = tid & 63, w = tid >> 6;
    const int l31 = l & 31, hi = l >> 5;
    const int bid = blockIdx.x;
    const int nwg = 512 * SPLIT;
    const int wg = (bid & 7) * (nwg >> 3) + (bid >> 3);  // chunked XCD swizzle
    const int part = wg & (SPLIT - 1);
    const int qt = (wg >> LS) & 15;
    const int head = wg >> (4 + LS);
    const int b = head >> 4, h = head & 15;
    const size_t hstride = (size_t)2048 * 64;
    const int kvlen = 2048 / SPLIT;
    const _Float16* Q = qkv + (size_t)((0 + b) * 16 + h) * hstride;
    const _Float16* Kp = qkv + (size_t)((2 + b) * 16 + h) * hstride + (size_t)part * kvlen * 64;
    const _Float16* Vp = qkv + (size_t)((4 + b) * 16 + h) * hstride + (size_t)part * kvlen * 64;
    const int NIT = kvlen / 64;

    __shared__ __align__(16) _Float16 Kl[2][64 * 64];  // [k][d], chunk ^= (k&7)
    __shared__ __align__(16) _Float16 Vt[2][64 * 64];  // [d][k], slot ^= (d&7)^((d>>3)&7)

    const int r0q = qt * 128 + w * 32;
    half8 qf[4];
    {
        const _Float16* Qrow = Q + (size_t)(r0q + l31) * 64 + 8 * hi;
#pragma unroll
        for (int dk = 0; dk < 4; dk++) qf[dk] = *(const half8*)&Qrow[16 * dk];
    }

    const int srow = l >> 3, sch = l & 7;
    auto stageK = [&](int it, _Float16* dst) {
#pragma unroll
        for (int t = 0; t < 2; t++) {
            int r0 = 16 * w + 8 * t;
            const _Float16* g = Kp + (size_t)(it * 64 + r0 + srow) * 64 + 8 * (sch ^ srow);
            GLOAD16(g, &dst[r0 * 64]);
        }
    };
    auto loadScatterV = [&](int it, _Float16* dst) {
        const _Float16* g = Vp + (size_t)(it * 64 + 16 * w + srow) * 64 + 8 * sch;
        half8 v0 = *(const half8*)g;
        half8 v1 = *(const half8*)(g + 8 * 64);
        const int j0 = 16 * w + srow;
        const int d0 = 8 * sch;
#pragma unroll
        for (int i = 0; i < 8; i++) {
            const int sw = (i ^ sch) << 3;
            dst[(d0 + i) * 64 + (j0 ^ sw)] = v0[i];
            dst[(d0 + i) * 64 + ((j0 + 8) ^ sw)] = v1[i];
        }
    };

    float lrun = 0.f;
    f32x16 o0 = {}, o1 = {};

    stageK(0, Kl[0]);
    loadScatterV(0, Vt[0]);
    __syncthreads();

    const int kswz = (l31 & 7) << 3;
    const int vswz0 = ((l31 & 7) ^ (l31 >> 3)) << 3;
    const int vswz1 = vswz0 ^ (4 << 3);

    for (int it = 0; it < NIT; ++it) {
        const int cur = it & 1;
        const _Float16* Kc = Kl[cur];
        const _Float16* Vc = Vt[cur];
        if (it + 1 < NIT) stageK(it + 1, Kl[cur ^ 1]);  // async across compute

#pragma unroll
        for (int hf = 0; hf < 2; hf++) {
            f32x16 st = {};
#pragma unroll
            for (int dk = 0; dk < 4; dk++) {
                const int colr = 16 * dk + 8 * hi;
                half8 kf = *(const half8*)&Kc[(hf * 32 + l31) * 64 + (colr ^ kswz)];
                __builtin_amdgcn_s_setprio(1);
                st = MFMA32(kf, qf[dk], st);
                __builtin_amdgcn_s_setprio(0);
            }
#pragma unroll
            for (int r = 0; r < 16; r++) st[r] = exp2f(st[r]);
            lrun += (((st[0] + st[1]) + (st[2] + st[3])) +
                     ((st[4] + st[5]) + (st[6] + st[7]))) +
                    (((st[8] + st[9]) + (st[10] + st[11])) +
                     ((st[12] + st[13]) + (st[14] + st[15])));

#pragma unroll
            for (int cc = 0; cc < 2; cc++) {
                const int c = 2 * hf + cc;
                uint pk0 = __builtin_bit_cast(uint, __builtin_amdgcn_cvt_pkrtz(st[cc * 8 + 0], st[cc * 8 + 1]));
                uint pk1 = __builtin_bit_cast(uint, __builtin_amdgcn_cvt_pkrtz(st[cc * 8 + 2], st[cc * 8 + 3]));
                uint pk2 = __builtin_bit_cast(uint, __builtin_amdgcn_cvt_pkrtz(st[cc * 8 + 4], st[cc * 8 + 5]));
                uint pk3 = __builtin_bit_cast(uint, __builtin_amdgcn_cvt_pkrtz(st[cc * 8 + 6], st[cc * 8 + 7]));
                uint2v s02 = __builtin_amdgcn_permlane32_swap(pk0, pk2, false, false);
                uint2v s13 = __builtin_amdgcn_permlane32_swap(pk1, pk3, false, false);
                uint4v fu = {s02.x, s13.x, s02.y, s13.y};
                half8 pfrag = __builtin_bit_cast(half8, fu);
                const int colc = 16 * c + 8 * hi;
                half8 vf0 = *(const half8*)&Vc[l31 * 64 + (colc ^ vswz0)];
                half8 vf1 = *(const half8*)&Vc[(32 + l31) * 64 + (colc ^ vswz1)];
                __builtin_amdgcn_s_setprio(1);
                o0 = MFMA32(vf0, pfrag, o0);
                o1 = MFMA32(vf1, pfrag, o1);
                __builtin_amdgcn_s_setprio(0);
            }
        }

        if (it + 1 < NIT) loadScatterV(it + 1, Vt[cur ^ 1]);
        __syncthreads();
    }

    lrun += __shfl_xor(lrun, 32);
    const int tok = r0q + l31;
    if (SPLIT > 1) {
        _Float16* orow = out + (size_t)part * 4194304 + (size_t)(b * 2048 + tok) * 1024 + h * 64;
#pragma unroll
        for (int g = 0; g < 4; g++) {
            half4 h4a, h4b;
#pragma unroll
            for (int j = 0; j < 4; j++) {
                h4a[j] = (_Float16)o0[4 * g + j];
                h4b[j] = (_Float16)o1[4 * g + j];
            }
            *(half4*)&orow[8 * g + 4 * hi] = h4a;
            *(half4*)&orow[32 + 8 * g + 4 * hi] = h4b;
        }
        if (!hi) lpart[part * 65536 + (b * 16 + h) * 2048 + tok] = lrun;
    } else {
        const float inv = __builtin_amdgcn_rcpf(lrun);
        _Float16* orow = out + (size_t)(b * 2048 + tok) * 1024 + h * 64;
#pragma unroll
        for (int g = 0; g < 4; g++) {
            half4 h4a, h4b;
#pragma unroll
            for (int j = 0; j < 4; j++) {
                h4a[j] = (_Float16)(o0[4 * g + j] * inv);
                h4b[j] = (_Float16)(o1[4 * g + j] * inv);
            }
            *(half4*)&orow[8 * g + 4 * hi] = h4a;
            *(half4*)&orow[32 + 8 * g + 4 * hi] = h4b;
        }
    }
}

// ---------------------------------------------------------------- split-KV merge (2 partials)
__global__ __launch_bounds__(256) void merge_attn2(const _Float16* __restrict__ onum,
                                                   const float* __restrict__ lpart,
                                                   _Float16* __restrict__ attnh) {
    const int i = blockIdx.x * 256 + threadIdx.x;  // [0, 524288) half8 units
    const int tokb = i >> 7;
    const int c0 = (i & 127) * 8;
    const int h = c0 >> 6;
    const int bb = tokb >> 11, tok = tokb & 2047;
    const int li = (bb * 16 + h) * 2048 + tok;
    float lt = lpart[li] + lpart[65536 + li];
    float inv = __builtin_amdgcn_rcpf(lt);
    float acc[8] = {};
#pragma unroll
    for (int q = 0; q < 2; q++) {
        half8 v = *(const half8*)&onum[(size_t)q * 4194304 + (size_t)tokb * 1024 + c0];
#pragma unroll
        for (int j = 0; j < 8; j++) acc[j] += (float)v[j];
    }
    half8 o;
#pragma unroll
    for (int j = 0; j < 8; j++) o[j] = (_Float16)(acc[j] * inv);
    *(half8*)&attnh[(size_t)tokb * 1024 + c0] = o;
}

// ---------------------------------------------------------------- launch
extern "C" void kernel_launch(void* const* d_in, const int* in_sizes, int n_in,
                              void* d_out, int out_size, void* d_ws, size_t ws_size,
                              hipStream_t stream) {
    const float* x = (const float*)d_in[0];
    const float* w_qkv = (const float*)d_in[1];
    const float* b_qkv = (const float*)d_in[2];
    const float* q_gamma = (const float*)d_in[3];
    const float* q_beta = (const float*)d_in[4];
    const float* k_gamma = (const float*)d_in[5];
    const float* k_beta = (const float*)d_in[6];
    const float* w_proj = (const float*)d_in[7];
    const float* b_proj = (const float*)d_in[8];

    char* ws = (char*)d_ws;
    _Float16* xh = (_Float16*)(ws + 0);             // 4096*1024
    _Float16* wqkvh = (_Float16*)(ws + 8388608);    // 3072*1024
    _Float16* wprojh = (_Float16*)(ws + 14680064);  // 1024*1024
    _Float16* qkvh = (_Float16*)(ws + 16777216);    // 3*2*16*2048*64
    _Float16* attnh = (_Float16*)(ws + 41943040);   // 4096*1024
    _Float16* onum = (_Float16*)(ws + 50331648);    // 2 * 4096*1024 fp16 = 16 MB
    float* lp = (float*)(ws + 67108864);            // 2 * 65536 f32 = 512 KB
    const bool split = ws_size >= 67633152;

    cvt_all<<<4096, 256, 0, stream>>>(x, w_qkv, w_proj, xh, wqkvh, wprojh);

    // gemm1: 4096x3072, 128^2 tiles -> grid 32x24 = 768 wgs; XCD rects 8m x 12n (5 MB/XCD)
    gemm_nt<4, 4, 0, 3, 12><<<dim3(32, 24), 256, 0, stream>>>(
        xh, wqkvh, b_qkv, (void*)qkvh, 1024, q_gamma, q_beta, k_gamma, k_beta);

    if (split) {
        attn_kernel<2><<<1024, 256, 0, stream>>>(qkvh, onum, lp);
        merge_attn2<<<2048, 256, 0, stream>>>(onum, lp, attnh);
    } else {
        attn_kernel<1><<<512, 256, 0, stream>>>(qkvh, attnh, nullptr);
    }

    // gemm2: 4096x1024, 64x128 tiles -> grid 64x8 = 512 wgs; XCD rects 16m x 4n (3 MB/XCD)
    gemm_nt<2, 4, 1, 4, 4><<<dim3(64, 8), 256, 0, stream>>>(
        attnh, wprojh, b_proj, d_out, 1024, nullptr, nullptr, nullptr, nullptr);
}